// Round 11
// baseline (4994.692 us; speedup 1.0000x reference)
//
#include <hip/hip_runtime.h>
#include <math.h>

typedef unsigned long long ull;

constexpr int Bn = 32, Tn = 64, Hn = 320, Jn = 320, Vn = 1024, Sn = 128;
constexpr int G4n = 1280, VP1 = 1025, WO4S = 1028;

// workspace layout (float units) -- ~11.9 MB
constexpr int OFF_XP   = 0;                       // 32*64*320
constexpr int OFF_G    = OFF_XP + Bn*Tn*Jn;       // 1024*1280
constexpr int OFF_WO4  = OFF_G + Vn*G4n;          // 80*1028*4
constexpr int OFF_WH4  = OFF_WO4 + 80*WO4S*4;     // 80*1280*4
constexpr int OFF_WP4  = OFF_WH4 + 80*G4n*4;      // 80*320*4
constexpr int OFF_RECG = OFF_WP4 + 80*Jn*4;       // 32 groups * 2 * 1280 ull tagged gg atoms
constexpr int OFF_KEY  = OFF_RECG + Bn*2*G4n*2;   // 32 groups * 2 parities * 32 ull
constexpr int MEMSET_FLOATS = Bn*2*G4n*2 + Bn*2*32*2;

#define AL(p)    __hip_atomic_load((p), __ATOMIC_RELAXED, __HIP_MEMORY_SCOPE_AGENT)
#define AS(p, v) __hip_atomic_store((p), (v), __ATOMIC_RELAXED, __HIP_MEMORY_SCOPE_AGENT)

__device__ __forceinline__ float sigmf(float x) { return 1.0f / (1.0f + expf(-x)); }

// key = mapped_val(32) | epoch(21 bits) | (2047-idx)(11 bits); bigger = better
__device__ __forceinline__ ull pack_key_e(float v, int idx, int es) {
    unsigned u = __float_as_uint(v);
    u = (u & 0x80000000u) ? ~u : (u | 0x80000000u);
    return ((ull)u << 32) | ((ull)(unsigned)es << 11) | (unsigned)(2047 - idx);
}
__device__ __forceinline__ float key_val_e(ull k) {
    unsigned u = (unsigned)(k >> 32);
    return __uint_as_float((u & 0x80000000u) ? (u & 0x7FFFFFFFu) : ~u);
}
__device__ __forceinline__ int key_idx_e(ull k) { return 2047 - (int)(k & 0x7FF); }
__device__ __forceinline__ int key_ep_e(ull k)  { return (int)((k >> 11) & 0x1FFFFF); }

// tagged gg atom read: wait until generation tag satisfied
__device__ __forceinline__ float gg_read(const ull* p, unsigned need) {
    ull a = AL(p);
    while ((unsigned)(a >> 32) < need) { __builtin_amdgcn_s_sleep(1); a = AL(p); }
    return __uint_as_float((unsigned)a);
}

// ---------------- generic tiled f32 GEMM: C = A@B + bias ----------------
__global__ __launch_bounds__(256) void gemm_bias(const float* __restrict__ A,
                                                 const float* __restrict__ Bm,
                                                 const float* __restrict__ bias,
                                                 float* __restrict__ C,
                                                 int M, int N, int K) {
    __shared__ float As[16][65];
    __shared__ float Bs[16][65];
    const int tx = threadIdx.x & 15, ty = threadIdx.x >> 4;
    const int n0 = blockIdx.x * 64, m0 = blockIdx.y * 64;
    float acc[4][4] = {};
    for (int k0 = 0; k0 < K; k0 += 16) {
        for (int i = threadIdx.x; i < 1024; i += 256) {
            int mm = i >> 4, kk = i & 15;
            As[kk][mm] = A[(m0 + mm) * K + k0 + kk];
            int kk2 = i >> 6, nn = i & 63;
            Bs[kk2][nn] = Bm[(k0 + kk2) * N + n0 + nn];
        }
        __syncthreads();
#pragma unroll
        for (int kk = 0; kk < 16; ++kk) {
            float av[4], bv[4];
#pragma unroll
            for (int r = 0; r < 4; ++r) { av[r] = As[kk][ty * 4 + r]; bv[r] = Bs[kk][tx * 4 + r]; }
#pragma unroll
            for (int i2 = 0; i2 < 4; ++i2)
#pragma unroll
                for (int j2 = 0; j2 < 4; ++j2) acc[i2][j2] += av[i2] * bv[j2];
        }
        __syncthreads();
    }
#pragma unroll
    for (int i2 = 0; i2 < 4; ++i2)
#pragma unroll
        for (int j2 = 0; j2 < 4; ++j2)
            C[(m0 + ty * 4 + i2) * N + n0 + tx * 4 + j2] = acc[i2][j2] + bias[n0 + tx * 4 + j2];
}

// ---------------- k4-interleave repacks: W4[k/4][col][4] = W[k][col] ----------------
__global__ __launch_bounds__(256) void repack_wout4(const float* __restrict__ W,
                                                    float* __restrict__ W4) {
    const int k4 = blockIdx.x;
    for (int c = threadIdx.x; c < VP1; c += 256) {
        float4 v;
        v.x = W[(k4 * 4 + 0) * VP1 + c];
        v.y = W[(k4 * 4 + 1) * VP1 + c];
        v.z = W[(k4 * 4 + 2) * VP1 + c];
        v.w = W[(k4 * 4 + 3) * VP1 + c];
        ((float4*)W4)[(size_t)k4 * WO4S + c] = v;
    }
}
__global__ __launch_bounds__(256) void repack_whh4(const float* __restrict__ W,
                                                   float* __restrict__ W4) {
    const int k4 = blockIdx.x;
    for (int c = threadIdx.x; c < G4n; c += 256) {
        float4 v;
        v.x = W[(k4 * 4 + 0) * G4n + c];
        v.y = W[(k4 * 4 + 1) * G4n + c];
        v.z = W[(k4 * 4 + 2) * G4n + c];
        v.w = W[(k4 * 4 + 3) * G4n + c];
        ((float4*)W4)[(size_t)k4 * G4n + c] = v;
    }
}
__global__ __launch_bounds__(256) void repack_wpred4(const float* __restrict__ W,
                                                     float* __restrict__ W4) {
    const int k4 = blockIdx.x;
    for (int c = threadIdx.x; c < Jn; c += 256) {
        float4 v;
        v.x = W[(k4 * 4 + 0) * Jn + c];
        v.y = W[(k4 * 4 + 1) * Jn + c];
        v.z = W[(k4 * 4 + 2) * Jn + c];
        v.w = W[(k4 * 4 + 3) * Jn + c];
        ((float4*)W4)[(size_t)k4 * Jn + c] = v;
    }
}

// ---------------- decode: 8 WGs / batch element; ONE round-trip per step ----------------
__global__ __launch_bounds__(256, 1) void rnnt_decode(
    const float* __restrict__ xp, const float* __restrict__ Gm,
    const float* __restrict__ Wo4, const float* __restrict__ Wh4,
    const float* __restrict__ Wp4,
    const float* __restrict__ b_out, const float* __restrict__ b_lstm,
    const float* __restrict__ b_pred, const int* __restrict__ out_len,
    ull* __restrict__ recG, ull* __restrict__ keyG, float* __restrict__ out) {
    __shared__ __align__(16) float f_s[Jn];
    __shared__ __align__(16) float h_s[Hn];
    __shared__ float c_s[Hn];
    __shared__ float dec_s[Jn];
    __shared__ float xpA[Jn], xpB[Jn];
    __shared__ ull bk_s;

    const int w = blockIdx.x, tid = threadIdx.x;
    const int b = w & 31, m = w >> 5;
    const int ol = out_len[b];
    const float* xpb = xp + b * Tn * Jn;
    ull* gbuf = recG + (size_t)b * 2 * G4n;      // 2 generation-parity gg buffers
    ull* keyb = keyG + (size_t)b * 64;           // 2 step-parity key buffers x 32

    const float4* Wo4f = (const float4*)Wo4;
    const float4* Wh4f = (const float4*)Wh4;
    const float4* Wp4f = (const float4*)Wp4;
    const float4* h4 = (const float4*)h_s;
    const float4* f4 = (const float4*)f_s;

    // ==== prologue (fully replicated, no communication): h0,c0, FULL dec0 -> f0 ====
    for (int r = tid; r < Hn; r += 256) {
        float c0 = sigmf(b_lstm[r]) * tanhf(b_lstm[2 * Hn + r]);
        float h0 = sigmf(b_lstm[3 * Hn + r]) * tanhf(c0);
        c_s[r] = c0; h_s[r] = h0;
    }
    __syncthreads();
    for (int c = tid; c < Jn; c += 256) {
        float ax = 0.f, ay = 0.f, az = 0.f, aw = 0.f;
#pragma unroll 10
        for (int k4 = 0; k4 < 80; ++k4) {
            float4 wv = Wp4f[(size_t)k4 * Jn + c];
            float4 hv = h4[k4];
            ax += wv.x * hv.x; ay += wv.y * hv.y;
            az += wv.z * hv.z; aw += wv.w * hv.w;
        }
        float d = b_pred[c] + ax + ay + az + aw;
        dec_s[c] = d;
        float fv = xpb[c] + d;
        f_s[c] = fv > 0.0f ? fv : 0.0f;
    }
    __syncthreads();

    // ==== step loop ====
    int told = 0, sold = 0, lenacc = 0, q = 1;
    unsigned g = 0;
    bool hdirty = true;
    int s = 0;
    for (; s < Sn; ++s) {
        if (told >= ol) break;
        const int es = s + 1;
        ull* keyp = keyb + (s & 1) * 32;
        if (hdirty) { q ^= 1; ++g; }
        ull* gq = gbuf + (size_t)q * G4n;

        // ---- xp prefetch (both tnew candidates) ----
        {
            const int tA = told, tB = (told + 1 < Tn - 1) ? told + 1 : (Tn - 1);
            xpA[tid] = xpb[tA * Jn + tid];
            xpB[tid] = xpb[tB * Jn + tid];
            if (tid < 64) {
                xpA[256 + tid] = xpb[tA * Jn + 256 + tid];
                xpB[256 + tid] = xpb[tB * Jn + 256 + tid];
            }
        }
        // ---- Phase A: waves 0-1 logits slice; waves 2-3 gates slice (concurrent) ----
        if (tid < 128) {
            const int c = m * 128 + tid;
            float ax = 0.f, ay = 0.f, az = 0.f, aw = 0.f;
#pragma unroll 20
            for (int k4 = 0; k4 < 80; ++k4) {
                float4 wv = Wo4f[(size_t)k4 * WO4S + c];
                float4 fv = f4[k4];
                ax += wv.x * fv.x; ay += wv.y * fv.y;
                az += wv.z * fv.z; aw += wv.w * fv.w;
            }
            ull key = pack_key_e(ax + ay + az + aw + b_out[c], c, es);
#pragma unroll
            for (int d = 1; d < 64; d <<= 1) {
                ull o = __shfl_xor(key, d, 64);
                if (o > key) key = o;
            }
            if ((tid & 63) == 0) AS(keyp + m * 2 + (tid >> 6), key);
        } else {
            const int c1 = tid - 128;
            if (hdirty) {
                {
                    const int c = m * 160 + c1;
                    float ax = 0.f, ay = 0.f, az = 0.f, aw = 0.f;
#pragma unroll 20
                    for (int k4 = 0; k4 < 80; ++k4) {
                        float4 wv = Wh4f[(size_t)k4 * G4n + c];
                        float4 hv = h4[k4];
                        ax += wv.x * hv.x; ay += wv.y * hv.y;
                        az += wv.z * hv.z; aw += wv.w * hv.w;
                    }
                    AS(gq + c, ((ull)g << 32) | __float_as_uint(ax + ay + az + aw));
                }
                if (c1 < 32) {
                    const int c = m * 160 + 128 + c1;
                    float ax = 0.f, ay = 0.f, az = 0.f, aw = 0.f;
#pragma unroll 20
                    for (int k4 = 0; k4 < 80; ++k4) {
                        float4 wv = Wh4f[(size_t)k4 * G4n + c];
                        float4 hv = h4[k4];
                        ax += wv.x * hv.x; ay += wv.y * hv.y;
                        az += wv.z * hv.z; aw += wv.w * hv.w;
                    }
                    AS(gq + c, ((ull)g << 32) | __float_as_uint(ax + ay + az + aw));
                }
            }
            if (m == 7 && tid >= 192) {   // blank column 1024 on wave 3
                const int l = tid - 192;
                float4 wv = Wo4f[(size_t)l * WO4S + Vn];
                float4 fv = f4[l];
                float p = wv.x * fv.x + wv.y * fv.y + wv.z * fv.z + wv.w * fv.w;
                if (l < 16) {
                    float4 wv2 = Wo4f[(size_t)(64 + l) * WO4S + Vn];
                    float4 fv2 = f4[64 + l];
                    p += wv2.x * fv2.x + wv2.y * fv2.y + wv2.z * fv2.z + wv2.w * fv2.w;
                }
#pragma unroll
                for (int d = 1; d < 64; d <<= 1) p += __shfl_xor(p, d, 64);
                if (l == 0) AS(keyp + 16, pack_key_e(p + b_out[Vn], Vn, es));
            }
        }
        // ---- the ONE round-trip: wave 0 polls 17 tagged keys ----
        if (tid < 64) {
            ull k = 0;
            if (tid < 17) {
                k = AL(keyp + tid);
                while (key_ep_e(k) < es) { __builtin_amdgcn_s_sleep(1); k = AL(keyp + tid); }
            }
#pragma unroll
            for (int d = 1; d < 64; d <<= 1) {
                ull o = __shfl_xor(k, d, 64);
                if (o > k) k = o;
            }
            if (tid == 0) bk_s = k;
        }
        __syncthreads();
        // ---- decode logic (replicated) ----
        const ull bk = bk_s;
        const int label = key_idx_e(bk);
        const bool emit = (label != Vn);
        int sym2 = emit ? sold + 1 : 0;
        const bool force = emit && (sym2 >= 2);
        const bool advance = (!emit) || force;
        const int tnew = told + (advance ? 1 : 0);
        sym2 = advance ? 0 : sym2;
        if (m == 0 && tid == 0) {
            out[s * Bn + b] = emit ? (float)label : 1024.0f;
            out[Sn * Bn + s * Bn + b] = key_val_e(bk);
            out[2 * Sn * Bn + s * Bn + b] = (float)told;
            if (emit) lenacc++;
        }
        if (emit) {
            // ---- LSTM: tagged gg atom reads (published this step, phase A) ----
            const float* gE = Gm + (size_t)label * G4n;
            {
                int r0 = tid;
                ull a0 = AL(gq + r0), a1 = AL(gq + Hn + r0);
                ull a2 = AL(gq + 2 * Hn + r0), a3 = AL(gq + 3 * Hn + r0);
                float xi = ((unsigned)(a0 >> 32) >= g) ? __uint_as_float((unsigned)a0) : gg_read(gq + r0, g);
                float xf = ((unsigned)(a1 >> 32) >= g) ? __uint_as_float((unsigned)a1) : gg_read(gq + Hn + r0, g);
                float xg = ((unsigned)(a2 >> 32) >= g) ? __uint_as_float((unsigned)a2) : gg_read(gq + 2 * Hn + r0, g);
                float xo = ((unsigned)(a3 >> 32) >= g) ? __uint_as_float((unsigned)a3) : gg_read(gq + 3 * Hn + r0, g);
                xi += gE[r0]; xf += gE[Hn + r0]; xg += gE[2 * Hn + r0]; xo += gE[3 * Hn + r0];
                float c2 = sigmf(xf) * c_s[r0] + sigmf(xi) * tanhf(xg);
                float h2 = sigmf(xo) * tanhf(c2);
                c_s[r0] = c2; h_s[r0] = h2;
                if (tid < 64) {
                    int r1 = 256 + tid;
                    ull b0 = AL(gq + r1), b1 = AL(gq + Hn + r1);
                    ull b2 = AL(gq + 2 * Hn + r1), b3 = AL(gq + 3 * Hn + r1);
                    float yi = ((unsigned)(b0 >> 32) >= g) ? __uint_as_float((unsigned)b0) : gg_read(gq + r1, g);
                    float yf = ((unsigned)(b1 >> 32) >= g) ? __uint_as_float((unsigned)b1) : gg_read(gq + Hn + r1, g);
                    float yg = ((unsigned)(b2 >> 32) >= g) ? __uint_as_float((unsigned)b2) : gg_read(gq + 2 * Hn + r1, g);
                    float yo = ((unsigned)(b3 >> 32) >= g) ? __uint_as_float((unsigned)b3) : gg_read(gq + 3 * Hn + r1, g);
                    yi += gE[r1]; yf += gE[Hn + r1]; yg += gE[2 * Hn + r1]; yo += gE[3 * Hn + r1];
                    float c2b = sigmf(yf) * c_s[r1] + sigmf(yi) * tanhf(yg);
                    float h2b = sigmf(yo) * tanhf(c2b);
                    c_s[r1] = c2b; h_s[r1] = h2b;
                }
            }
            __syncthreads();   // h_s complete
            // ---- FULL dec GEMV (local, replaces the f round-trip) + f build ----
            const float* xprow = advance ? xpB : xpA;
            {
                const int c = tid;
                float ax = 0.f, ay = 0.f, az = 0.f, aw = 0.f;
#pragma unroll 20
                for (int k4 = 0; k4 < 80; ++k4) {
                    float4 wv = Wp4f[(size_t)k4 * Jn + c];
                    float4 hv = h4[k4];
                    ax += wv.x * hv.x; ay += wv.y * hv.y;
                    az += wv.z * hv.z; aw += wv.w * hv.w;
                }
                float d = b_pred[c] + ax + ay + az + aw;
                dec_s[c] = d;
                float fv = xprow[c] + d;
                f_s[c] = fv > 0.0f ? fv : 0.0f;
            }
            if (tid < 64) {
                const int c = 256 + tid;
                float ax = 0.f, ay = 0.f, az = 0.f, aw = 0.f;
#pragma unroll 20
                for (int k4 = 0; k4 < 80; ++k4) {
                    float4 wv = Wp4f[(size_t)k4 * Jn + c];
                    float4 hv = h4[k4];
                    ax += wv.x * hv.x; ay += wv.y * hv.y;
                    az += wv.z * hv.z; aw += wv.w * hv.w;
                }
                float d = b_pred[c] + ax + ay + az + aw;
                dec_s[c] = d;
                float fv = xprow[c] + d;
                f_s[c] = fv > 0.0f ? fv : 0.0f;
            }
        } else {
            // blank step: dec unchanged, f from cached dec + advanced xp row
            float fv = xpB[tid] + dec_s[tid];
            f_s[tid] = fv > 0.0f ? fv : 0.0f;
            if (tid < 64) {
                float fv2 = xpB[256 + tid] + dec_s[256 + tid];
                f_s[256 + tid] = fv2 > 0.0f ? fv2 : 0.0f;
            }
        }
        hdirty = emit; told = tnew; sold = sym2;
        __syncthreads();   // f_s/h_s ready for next step's phase A
    }
    // ---- tail fill + lengths (member 0) ----
    if (m == 0) {
        for (int ss = s + tid; ss < Sn; ss += 256) {
            out[ss * Bn + b] = 1024.0f;
            out[Sn * Bn + ss * Bn + b] = 0.0f;
            out[2 * Sn * Bn + ss * Bn + b] = (float)told;
        }
        if (tid == 0) out[3 * Sn * Bn + b] = (float)lenacc;
    }
}

extern "C" void kernel_launch(void* const* d_in, const int* in_sizes, int n_in,
                              void* d_out, int out_size, void* d_ws, size_t ws_size,
                              hipStream_t stream) {
    (void)in_sizes; (void)n_in; (void)out_size; (void)ws_size;
    const float* x      = (const float*)d_in[0];
    const int*   outlen = (const int*)d_in[1];
    const float* W_enc  = (const float*)d_in[2];
    const float* b_enc  = (const float*)d_in[3];
    const float* Emb    = (const float*)d_in[4];
    const float* W_ih   = (const float*)d_in[5];
    const float* W_hh   = (const float*)d_in[6];
    const float* b_lstm = (const float*)d_in[7];
    const float* W_pred = (const float*)d_in[8];
    const float* b_pred = (const float*)d_in[9];
    const float* W_out  = (const float*)d_in[10];
    const float* b_out  = (const float*)d_in[11];

    float* ws   = (float*)d_ws;
    float* xp   = ws + OFF_XP;
    float* Gm   = ws + OFF_G;
    float* Wo4  = ws + OFF_WO4;
    float* Wh4  = ws + OFF_WH4;
    float* Wp4  = ws + OFF_WP4;
    ull*   recG = (ull*)(ws + OFF_RECG);
    ull*   keyG = (ull*)(ws + OFF_KEY);

    // reset tagged-atom state (gg buffers + key buffers) every launch/replay
    hipMemsetAsync(recG, 0, (size_t)MEMSET_FLOATS * sizeof(float), stream);

    gemm_bias<<<dim3(5, 32), 256, 0, stream>>>(x, W_enc, b_enc, xp, Bn * Tn, Jn, 1024);
    gemm_bias<<<dim3(20, 16), 256, 0, stream>>>(Emb, W_ih, b_lstm, Gm, Vn, G4n, Hn);
    repack_wout4<<<80, 256, 0, stream>>>(W_out, Wo4);
    repack_whh4<<<80, 256, 0, stream>>>(W_hh, Wh4);
    repack_wpred4<<<80, 256, 0, stream>>>(W_pred, Wp4);

    rnnt_decode<<<256, 256, 0, stream>>>(xp, Gm, Wo4, Wh4, Wp4,
                                         b_out, b_lstm, b_pred, outlen,
                                         recG, keyG, (float*)d_out);
}

// Round 12
// 4315.462 us; speedup vs baseline: 1.1574x; 1.1574x over previous
//
#include <hip/hip_runtime.h>
#include <math.h>

typedef unsigned long long ull;

constexpr int Bn = 32, Tn = 64, Hn = 320, Jn = 320, Vn = 1024, Sn = 128;
constexpr int G4n = 1280, VP1 = 1025, WO4S = 1028;

// workspace layout (float units) -- ~11.7 MB
constexpr int OFF_XP   = 0;                       // 32*64*320
constexpr int OFF_G    = OFF_XP + Bn*Tn*Jn;       // 1024*1280
constexpr int OFF_WPT  = OFF_G + Vn*G4n;          // 320*320
constexpr int OFF_WO4  = OFF_WPT + Jn*Hn;         // 80*1028*4
constexpr int OFF_WH4  = OFF_WO4 + 80*WO4S*4;     // 80*1280*4
constexpr int OFF_GG   = OFF_WH4 + 80*G4n*4;      // 2*32*1280 gate values (flag-gated)
constexpr int OFF_RECF = OFF_GG + 2*Bn*G4n;       // 32*320 tagged f atoms (ull)
constexpr int OFF_KEY  = OFF_RECF + 2*Bn*Jn;      // 32*32 tagged key atoms (ull)
constexpr int OFF_FLG  = OFF_KEY + 2048;          // 32 * 16 flags * 32-int spread
constexpr int MEMSET_FLOATS = 2*Bn*Jn + 2048 + Bn*16*32;

#define AL(p)    __hip_atomic_load((p), __ATOMIC_RELAXED, __HIP_MEMORY_SCOPE_AGENT)
#define AS(p, v) __hip_atomic_store((p), (v), __ATOMIC_RELAXED, __HIP_MEMORY_SCOPE_AGENT)

__device__ __forceinline__ float sigmf(float x) { return 1.0f / (1.0f + expf(-x)); }

// key = mapped_val(32) | epoch(21 bits) | (2047-idx)(11 bits); bigger = better
__device__ __forceinline__ ull pack_key_e(float v, int idx, int es) {
    unsigned u = __float_as_uint(v);
    u = (u & 0x80000000u) ? ~u : (u | 0x80000000u);
    return ((ull)u << 32) | ((ull)(unsigned)es << 11) | (unsigned)(2047 - idx);
}
__device__ __forceinline__ float key_val_e(ull k) {
    unsigned u = (unsigned)(k >> 32);
    return __uint_as_float((u & 0x80000000u) ? (u & 0x7FFFFFFFu) : ~u);
}
__device__ __forceinline__ int key_idx_e(ull k) { return 2047 - (int)(k & 0x7FF); }
__device__ __forceinline__ int key_ep_e(ull k)  { return (int)((k >> 11) & 0x1FFFFF); }

// tagged f atom acquire: poll until tag >= need
__device__ __forceinline__ float facq(const ull* p, unsigned need) {
    ull a = AL(p);
    while ((unsigned)(a >> 32) < need) { __builtin_amdgcn_s_sleep(2); a = AL(p); }
    return __uint_as_float((unsigned)a);
}

// ---------------- generic tiled f32 GEMM: C = A@B + bias ----------------
__global__ __launch_bounds__(256) void gemm_bias(const float* __restrict__ A,
                                                 const float* __restrict__ Bm,
                                                 const float* __restrict__ bias,
                                                 float* __restrict__ C,
                                                 int M, int N, int K) {
    __shared__ float As[16][65];
    __shared__ float Bs[16][65];
    const int tx = threadIdx.x & 15, ty = threadIdx.x >> 4;
    const int n0 = blockIdx.x * 64, m0 = blockIdx.y * 64;
    float acc[4][4] = {};
    for (int k0 = 0; k0 < K; k0 += 16) {
        for (int i = threadIdx.x; i < 1024; i += 256) {
            int mm = i >> 4, kk = i & 15;
            As[kk][mm] = A[(m0 + mm) * K + k0 + kk];
            int kk2 = i >> 6, nn = i & 63;
            Bs[kk2][nn] = Bm[(k0 + kk2) * N + n0 + nn];
        }
        __syncthreads();
#pragma unroll
        for (int kk = 0; kk < 16; ++kk) {
            float av[4], bv[4];
#pragma unroll
            for (int r = 0; r < 4; ++r) { av[r] = As[kk][ty * 4 + r]; bv[r] = Bs[kk][tx * 4 + r]; }
#pragma unroll
            for (int i2 = 0; i2 < 4; ++i2)
#pragma unroll
                for (int j2 = 0; j2 < 4; ++j2) acc[i2][j2] += av[i2] * bv[j2];
        }
        __syncthreads();
    }
#pragma unroll
    for (int i2 = 0; i2 < 4; ++i2)
#pragma unroll
        for (int j2 = 0; j2 < 4; ++j2)
            C[(m0 + ty * 4 + i2) * N + n0 + tx * 4 + j2] = acc[i2][j2] + bias[n0 + tx * 4 + j2];
}

// ---------------- 320x320 transpose ----------------
__global__ __launch_bounds__(256) void transpose_pred(const float* __restrict__ W,
                                                      float* __restrict__ WT) {
    __shared__ float t[32][33];
    const int bx = blockIdx.x % 10, by = blockIdx.x / 10;
    const int lx = threadIdx.x & 31, ly = threadIdx.x >> 5;
#pragma unroll
    for (int r = 0; r < 32; r += 8)
        t[ly + r][lx] = W[(by * 32 + ly + r) * 320 + bx * 32 + lx];
    __syncthreads();
#pragma unroll
    for (int r = 0; r < 32; r += 8)
        WT[(bx * 32 + ly + r) * 320 + by * 32 + lx] = t[lx][ly + r];
}

// ---------------- k4-interleave repacks: W4[k/4][col][4] = W[k][col] ----------------
__global__ __launch_bounds__(256) void repack_wout4(const float* __restrict__ W,
                                                    float* __restrict__ W4) {
    const int k4 = blockIdx.x;
    for (int c = threadIdx.x; c < VP1; c += 256) {
        float4 v;
        v.x = W[(k4 * 4 + 0) * VP1 + c];
        v.y = W[(k4 * 4 + 1) * VP1 + c];
        v.z = W[(k4 * 4 + 2) * VP1 + c];
        v.w = W[(k4 * 4 + 3) * VP1 + c];
        ((float4*)W4)[(size_t)k4 * WO4S + c] = v;
    }
}
__global__ __launch_bounds__(256) void repack_whh4(const float* __restrict__ W,
                                                   float* __restrict__ W4) {
    const int k4 = blockIdx.x;
    for (int c = threadIdx.x; c < G4n; c += 256) {
        float4 v;
        v.x = W[(k4 * 4 + 0) * G4n + c];
        v.y = W[(k4 * 4 + 1) * G4n + c];
        v.z = W[(k4 * 4 + 2) * G4n + c];
        v.w = W[(k4 * 4 + 3) * G4n + c];
        ((float4*)W4)[(size_t)k4 * G4n + c] = v;
    }
}

// ---------------- decode: 8 WGs / batch element; 2 RT per step ----------------
__global__ __launch_bounds__(256, 1) void rnnt_decode(
    const float* __restrict__ xp, const float* __restrict__ Gm,
    const float* __restrict__ Wo4, const float* __restrict__ Wh4,
    const float* __restrict__ WpT, const float* __restrict__ Wpred,
    const float* __restrict__ b_out, const float* __restrict__ b_lstm,
    const float* __restrict__ b_pred, const int* __restrict__ out_len,
    ull* __restrict__ recF, float* __restrict__ gG, ull* __restrict__ keyG,
    int* __restrict__ flgG, float* __restrict__ out) {
    __shared__ __align__(16) float f_s[Jn];
    __shared__ __align__(16) float h_s[Hn];
    __shared__ float c_s[Hn];
    __shared__ float gg_s[G4n];
    __shared__ float dec_s[40];
    __shared__ float xpA[40], xpB[40];
    __shared__ ull bk_s;

    const int w = blockIdx.x, tid = threadIdx.x;
    const int b = w & 31, m = w >> 5;
    const int ol = out_len[b];
    const float* xpb = xp + b * Tn * Jn;
    ull*  recF8 = recF + (size_t)b * Jn;        // 320 tagged f atoms
    ull*  keysb = keyG + (size_t)b * 32;        // 17 tagged key slots
    int*  ggfb  = flgG + b * 512;               // 16 gate flags, 32-int spread

    const float4* Wo4f = (const float4*)Wo4;
    const float4* Wh4f = (const float4*)Wh4;
    const float4* h4 = (const float4*)h_s;
    const float4* f4 = (const float4*)f_s;

    // ==== prologue (replicated): h0, c0, full dec0 -> f0 local; own dec slice ====
    for (int r = tid; r < Hn; r += 256) {
        float c0 = sigmf(b_lstm[r]) * tanhf(b_lstm[2 * Hn + r]);
        float h0 = sigmf(b_lstm[3 * Hn + r]) * tanhf(c0);
        c_s[r] = c0; h_s[r] = h0;
    }
    __syncthreads();
    for (int c = tid; c < Jn; c += 256) {
        const float* wp = Wpred + c;
        float d0 = 0.0f, d1 = 0.0f;
#pragma unroll 8
        for (int k = 0; k < 160; ++k) {
            d0 += h_s[k] * wp[k * Jn];
            d1 += h_s[k + 160] * wp[(k + 160) * Jn];
        }
        float d = b_pred[c] + d0 + d1;
        float fv = xpb[c] + d;
        f_s[c] = fv > 0.0f ? fv : 0.0f;
        int lc = c - m * 40;
        if (lc >= 0 && lc < 40) dec_s[lc] = d;
    }
    __syncthreads();

    // ==== step loop ====
    int told = 0, sold = 0, lenacc = 0, q = 1;
    bool hdirty = true;
    int s = 0;
    for (; s < Sn; ++s) {
        if (told >= ol) break;
        const int es = s + 1;
        if (hdirty) q ^= 1;
        float* gq = gG + (size_t)(q * Bn + b) * G4n;

        // ===== pre-barrier: waves 0-1 acquire f; waves 2-3 compute+publish gates =====
        if (tid < 128) {
            if (s > 0) {
                const unsigned need = (unsigned)s;
                ull a0 = AL(recF8 + tid);
                ull a1 = AL(recF8 + tid + 128);
                ull a2 = 0;
                if (tid < 64) a2 = AL(recF8 + tid + 256);
                float v0 = ((unsigned)(a0 >> 32) >= need) ? __uint_as_float((unsigned)a0)
                                                          : facq(recF8 + tid, need);
                float v1 = ((unsigned)(a1 >> 32) >= need) ? __uint_as_float((unsigned)a1)
                                                          : facq(recF8 + tid + 128, need);
                f_s[tid] = v0;
                f_s[tid + 128] = v1;
                if (tid < 64) {
                    float v2 = ((unsigned)(a2 >> 32) >= need) ? __uint_as_float((unsigned)a2)
                                                              : facq(recF8 + tid + 256, need);
                    f_s[tid + 256] = v2;
                }
            }
        } else if (hdirty) {
            const int c1 = tid - 128;
            {
                const int c = m * 160 + c1;
                float ax = 0.f, ay = 0.f, az = 0.f, aw = 0.f;
#pragma unroll 20
                for (int k4 = 0; k4 < 80; ++k4) {
                    float4 wv = Wh4f[(size_t)k4 * G4n + c];
                    float4 hv = h4[k4];
                    ax += wv.x * hv.x; ay += wv.y * hv.y;
                    az += wv.z * hv.z; aw += wv.w * hv.w;
                }
                AS(gq + c, ax + ay + az + aw);
            }
            if (c1 < 32) {
                const int c = m * 160 + 128 + c1;
                float ax = 0.f, ay = 0.f, az = 0.f, aw = 0.f;
#pragma unroll 20
                for (int k4 = 0; k4 < 80; ++k4) {
                    float4 wv = Wh4f[(size_t)k4 * G4n + c];
                    float4 hv = h4[k4];
                    ax += wv.x * hv.x; ay += wv.y * hv.y;
                    az += wv.z * hv.z; aw += wv.w * hv.w;
                }
                AS(gq + c, ax + ay + az + aw);
            }
            asm volatile("s_waitcnt vmcnt(0)" ::: "memory");
            if (tid == 128 || tid == 192)
                AS(ggfb + (m * 2 + ((tid - 128) >> 6)) * 32, es);
        }
        __syncthreads();   // syncA: f_s ready; gates published
        // ===== post-A: logits (waves 0-1); key/gg waits overlapped =====
        if (tid < 128) {
            const int c = m * 128 + tid;
            float ax = 0.f, ay = 0.f, az = 0.f, aw = 0.f;
#pragma unroll 20
            for (int k4 = 0; k4 < 80; ++k4) {
                float4 wv = Wo4f[(size_t)k4 * WO4S + c];
                float4 fv = f4[k4];
                ax += wv.x * fv.x; ay += wv.y * fv.y;
                az += wv.z * fv.z; aw += wv.w * fv.w;
            }
            ull key = pack_key_e(ax + ay + az + aw + b_out[c], c, es);
#pragma unroll
            for (int d = 1; d < 64; d <<= 1) {
                ull o = __shfl_xor(key, d, 64);
                if (o > key) key = o;
            }
            if ((tid & 63) == 0) AS(keysb + m * 2 + (tid >> 6), key);
        }
        if (tid < 64) {
            // wave 0: poll 17 tagged keys
            ull k = 0;
            if (tid < 17) {
                k = AL(keysb + tid);
                while (key_ep_e(k) < es) { __builtin_amdgcn_s_sleep(2); k = AL(keysb + tid); }
            }
#pragma unroll
            for (int d = 1; d < 64; d <<= 1) {
                ull o = __shfl_xor(k, d, 64);
                if (o > k) k = o;
            }
            if (tid == 0) bk_s = k;
        } else if (tid < 128) {
            // wave 1: xp row prefetch for both tnew candidates (own 40-col slice)
            const int j = tid - 64;
            if (j < 40) {
                const int tB = (told + 1 < Tn - 1) ? told + 1 : (Tn - 1);
                xpA[j] = xpb[told * Jn + m * 40 + j];
                xpB[j] = xpb[tB * Jn + m * 40 + j];
            }
        } else {
            // waves 2-3: blank col (m==7, wave 3) + flag-gated gg -> LDS
            if (m == 7 && tid >= 192) {
                const int l = tid - 192;
                float4 wv = Wo4f[(size_t)l * WO4S + Vn];
                float4 fv = f4[l];
                float p = wv.x * fv.x + wv.y * fv.y + wv.z * fv.z + wv.w * fv.w;
                if (l < 16) {
                    float4 wv2 = Wo4f[(size_t)(64 + l) * WO4S + Vn];
                    float4 fv2 = f4[64 + l];
                    p += wv2.x * fv2.x + wv2.y * fv2.y + wv2.z * fv2.z + wv2.w * fv2.w;
                }
#pragma unroll
                for (int d = 1; d < 64; d <<= 1) p += __shfl_xor(p, d, 64);
                if (l == 0) AS(keysb + 16, pack_key_e(p + b_out[Vn], Vn, es));
            }
            if (hdirty) {
                const int l = tid & 63;
                if (l < 16) {
                    int v = AL(ggfb + l * 32);
                    while (v < es) { __builtin_amdgcn_s_sleep(2); v = AL(ggfb + l * 32); }
                }
                const int u = tid - 128;
#pragma unroll
                for (int j2 = 0; j2 < 10; ++j2)
                    gg_s[u + 128 * j2] = AL(gq + u + 128 * j2);
            }
        }
        __syncthreads();   // syncB: bk_s, gg_s, xpA/xpB ready
        // ===== decode logic (replicated) =====
        const ull bk = bk_s;
        const int label = key_idx_e(bk);
        const bool emit = (label != Vn);
        int sym2 = emit ? sold + 1 : 0;
        const bool force = emit && (sym2 >= 2);
        const bool advance = (!emit) || force;
        const int tnew = told + (advance ? 1 : 0);
        sym2 = advance ? 0 : sym2;
        if (m == 0 && tid == 0) {
            out[s * Bn + b] = emit ? (float)label : 1024.0f;
            out[Sn * Bn + s * Bn + b] = key_val_e(bk);
            out[2 * Sn * Bn + s * Bn + b] = (float)told;
            if (emit) lenacc++;
        }
        // ===== LSTM from LDS (emit only) =====
        if (emit) {
            const float* gE = Gm + (size_t)label * G4n;
            {
                int r = tid;
                float xi = gg_s[r]          + gE[r];
                float xf = gg_s[Hn + r]     + gE[Hn + r];
                float xg = gg_s[2 * Hn + r] + gE[2 * Hn + r];
                float xo = gg_s[3 * Hn + r] + gE[3 * Hn + r];
                float c2 = sigmf(xf) * c_s[r] + sigmf(xi) * tanhf(xg);
                float h2 = sigmf(xo) * tanhf(c2);
                c_s[r] = c2; h_s[r] = h2;
            }
            if (tid < 64) {
                int r = 256 + tid;
                float xi = gg_s[r]          + gE[r];
                float xf = gg_s[Hn + r]     + gE[Hn + r];
                float xg = gg_s[2 * Hn + r] + gE[2 * Hn + r];
                float xo = gg_s[3 * Hn + r] + gE[3 * Hn + r];
                float c2 = sigmf(xf) * c_s[r] + sigmf(xi) * tanhf(xg);
                float h2 = sigmf(xo) * tanhf(c2);
                c_s[r] = c2; h_s[r] = h2;
            }
        }
        __syncthreads();   // syncC: h_s complete
        // ===== dec GEMV (own 40 cols, emit only) =====
        if (emit && tid < 160) {
            const int sc = tid >> 2, kk = tid & 3;
            const float* wr = WpT + (size_t)(m * 40 + sc) * Hn + kk * 80;
            const float4* hh4 = (const float4*)(h_s + kk * 80);
            float4 dv = make_float4(0.f, 0.f, 0.f, 0.f);
#pragma unroll 5
            for (int q2 = 0; q2 < 20; ++q2) {
                float4 wv = ((const float4*)wr)[q2];
                float4 hv = hh4[q2];
                dv.x += wv.x * hv.x; dv.y += wv.y * hv.y;
                dv.z += wv.z * hv.z; dv.w += wv.w * hv.w;
            }
            float d = dv.x + dv.y + dv.z + dv.w;
            d += __shfl_xor(d, 1, 64);
            d += __shfl_xor(d, 2, 64);
            if (kk == 0) dec_s[sc] = d + b_pred[m * 40 + sc];
        }
        __syncthreads();   // syncD: dec_s ready
        // ===== publish own f slice as tagged atoms (tag = es); no drain, no flag =====
        if (tid < 40) {
            const float fv0 = (advance ? xpB[tid] : xpA[tid]) + dec_s[tid];
            const float fr = fv0 > 0.0f ? fv0 : 0.0f;
            AS(recF8 + m * 40 + tid, ((ull)(unsigned)es << 32) | (ull)__float_as_uint(fr));
        }
        hdirty = emit; told = tnew; sold = sym2;
    }
    // ---- tail fill + lengths (member 0) ----
    if (m == 0) {
        for (int ss = s + tid; ss < Sn; ss += 256) {
            out[ss * Bn + b] = 1024.0f;
            out[Sn * Bn + ss * Bn + b] = 0.0f;
            out[2 * Sn * Bn + ss * Bn + b] = (float)told;
        }
        if (tid == 0) out[3 * Sn * Bn + b] = (float)lenacc;
    }
}

extern "C" void kernel_launch(void* const* d_in, const int* in_sizes, int n_in,
                              void* d_out, int out_size, void* d_ws, size_t ws_size,
                              hipStream_t stream) {
    (void)in_sizes; (void)n_in; (void)out_size; (void)ws_size;
    const float* x      = (const float*)d_in[0];
    const int*   outlen = (const int*)d_in[1];
    const float* W_enc  = (const float*)d_in[2];
    const float* b_enc  = (const float*)d_in[3];
    const float* Emb    = (const float*)d_in[4];
    const float* W_ih   = (const float*)d_in[5];
    const float* W_hh   = (const float*)d_in[6];
    const float* b_lstm = (const float*)d_in[7];
    const float* W_pred = (const float*)d_in[8];
    const float* b_pred = (const float*)d_in[9];
    const float* W_out  = (const float*)d_in[10];
    const float* b_out  = (const float*)d_in[11];

    float* ws   = (float*)d_ws;
    float* xp   = ws + OFF_XP;
    float* Gm   = ws + OFF_G;
    float* WpT  = ws + OFF_WPT;
    float* Wo4  = ws + OFF_WO4;
    float* Wh4  = ws + OFF_WH4;
    float* gG   = ws + OFF_GG;
    ull*   recF = (ull*)(ws + OFF_RECF);
    ull*   keyG = (ull*)(ws + OFF_KEY);
    int*   flgG = (int*)(ws + OFF_FLG);

    // reset tagged/flag state every launch/replay (tags restart at 0)
    hipMemsetAsync(recF, 0, (size_t)MEMSET_FLOATS * sizeof(float), stream);

    gemm_bias<<<dim3(5, 32), 256, 0, stream>>>(x, W_enc, b_enc, xp, Bn * Tn, Jn, 1024);
    gemm_bias<<<dim3(20, 16), 256, 0, stream>>>(Emb, W_ih, b_lstm, Gm, Vn, G4n, Hn);
    transpose_pred<<<100, 256, 0, stream>>>(W_pred, WpT);
    repack_wout4<<<80, 256, 0, stream>>>(W_out, Wo4);
    repack_whh4<<<80, 256, 0, stream>>>(W_hh, Wh4);

    rnnt_decode<<<256, 256, 0, stream>>>(xp, Gm, Wo4, Wh4, WpT, W_pred,
                                         b_out, b_lstm, b_pred, outlen,
                                         recF, gG, keyG, flgG, (float*)d_out);
}

// Round 13
// 2100.348 us; speedup vs baseline: 2.3780x; 2.0546x over previous
//
#include <hip/hip_runtime.h>
#include <math.h>

typedef unsigned long long ull;

constexpr int Bn = 32, Tn = 64, Hn = 320, Jn = 320, Vn = 1024, Sn = 128;
constexpr int G4n = 1280, VP1 = 1025, WO4S = 1028;

// workspace layout (float units) -- ~11.8 MB
constexpr int OFF_XP  = 0;                        // 32*64*320
constexpr int OFF_G   = OFF_XP + Bn*Tn*Jn;        // 1024*1280
constexpr int OFF_WO4 = OFF_G + Vn*G4n;           // 80*1028*4
constexpr int OFF_WH4 = OFF_WO4 + 80*WO4S*4;      // 80*1280*4
constexpr int OFF_WP4 = OFF_WH4 + 80*G4n*4;       // 80*320*4
constexpr int OFF_CB  = OFF_WP4 + 80*Jn*4;        // 2*32*320 c (emit-parity)
constexpr int OFF_DEC = OFF_CB + 2*Bn*Hn;         // 2*32*320 dec (emit-parity)
constexpr int OFF_GB  = OFF_DEC + 2*Bn*Jn;        // 2*32*1280 gates (emit-parity)
constexpr int OFF_KEY = OFF_GB + 2*Bn*G4n;        // 2*32*40 ull (step-parity)
constexpr int OFF_REC = OFF_KEY + 2*Bn*40*2;      // 2*32*4 int (step-parity)

__device__ __forceinline__ float sigmf(float x) { return 1.0f / (1.0f + expf(-x)); }

// monotonic (value,idx) pack: bigger float -> bigger key; tie -> smaller idx wins
__device__ __forceinline__ ull pack_key(float v, int idx) {
    unsigned u = __float_as_uint(v);
    u = (u & 0x80000000u) ? ~u : (u | 0x80000000u);
    return ((ull)u << 32) | (unsigned)(0x7FFFFFFF - idx);
}
__device__ __forceinline__ float key_val(ull k) {
    unsigned u = (unsigned)(k >> 32);
    return __uint_as_float((u & 0x80000000u) ? (u & 0x7FFFFFFFu) : ~u);
}
__device__ __forceinline__ int key_idx(ull k) { return 0x7FFFFFFF - (int)(k & 0xFFFFFFFFu); }

// ---------------- generic tiled f32 GEMM: C = A@B + bias ----------------
__global__ __launch_bounds__(256) void gemm_bias(const float* __restrict__ A,
                                                 const float* __restrict__ Bm,
                                                 const float* __restrict__ bias,
                                                 float* __restrict__ C,
                                                 int M, int N, int K) {
    __shared__ float As[16][65];
    __shared__ float Bs[16][65];
    const int tx = threadIdx.x & 15, ty = threadIdx.x >> 4;
    const int n0 = blockIdx.x * 64, m0 = blockIdx.y * 64;
    float acc[4][4] = {};
    for (int k0 = 0; k0 < K; k0 += 16) {
        for (int i = threadIdx.x; i < 1024; i += 256) {
            int mm = i >> 4, kk = i & 15;
            As[kk][mm] = A[(m0 + mm) * K + k0 + kk];
            int kk2 = i >> 6, nn = i & 63;
            Bs[kk2][nn] = Bm[(k0 + kk2) * N + n0 + nn];
        }
        __syncthreads();
#pragma unroll
        for (int kk = 0; kk < 16; ++kk) {
            float av[4], bv[4];
#pragma unroll
            for (int r = 0; r < 4; ++r) { av[r] = As[kk][ty * 4 + r]; bv[r] = Bs[kk][tx * 4 + r]; }
#pragma unroll
            for (int i2 = 0; i2 < 4; ++i2)
#pragma unroll
                for (int j2 = 0; j2 < 4; ++j2) acc[i2][j2] += av[i2] * bv[j2];
        }
        __syncthreads();
    }
#pragma unroll
    for (int i2 = 0; i2 < 4; ++i2)
#pragma unroll
        for (int j2 = 0; j2 < 4; ++j2)
            C[(m0 + ty * 4 + i2) * N + n0 + tx * 4 + j2] = acc[i2][j2] + bias[n0 + tx * 4 + j2];
}

// ---------------- k4-interleave repacks: W4[k/4][col][4] = W[k][col] ----------------
__global__ __launch_bounds__(256) void repack_wout4(const float* __restrict__ W,
                                                    float* __restrict__ W4) {
    const int k4 = blockIdx.x;
    for (int c = threadIdx.x; c < VP1; c += 256) {
        float4 v;
        v.x = W[(k4 * 4 + 0) * VP1 + c];
        v.y = W[(k4 * 4 + 1) * VP1 + c];
        v.z = W[(k4 * 4 + 2) * VP1 + c];
        v.w = W[(k4 * 4 + 3) * VP1 + c];
        ((float4*)W4)[(size_t)k4 * WO4S + c] = v;
    }
}
__global__ __launch_bounds__(256) void repack_whh4(const float* __restrict__ W,
                                                   float* __restrict__ W4) {
    const int k4 = blockIdx.x;
    for (int c = threadIdx.x; c < G4n; c += 256) {
        float4 v;
        v.x = W[(k4 * 4 + 0) * G4n + c];
        v.y = W[(k4 * 4 + 1) * G4n + c];
        v.z = W[(k4 * 4 + 2) * G4n + c];
        v.w = W[(k4 * 4 + 3) * G4n + c];
        ((float4*)W4)[(size_t)k4 * G4n + c] = v;
    }
}
__global__ __launch_bounds__(256) void repack_wpred4(const float* __restrict__ W,
                                                     float* __restrict__ W4) {
    const int k4 = blockIdx.x;
    for (int c = threadIdx.x; c < Jn; c += 256) {
        float4 v;
        v.x = W[(k4 * 4 + 0) * Jn + c];
        v.y = W[(k4 * 4 + 1) * Jn + c];
        v.z = W[(k4 * 4 + 2) * Jn + c];
        v.w = W[(k4 * 4 + 3) * Jn + c];
        ((float4*)W4)[(size_t)k4 * Jn + c] = v;
    }
}

// ---------------- one decode step per launch; 8 WGs per batch element ----------------
// Cross-WG data flows ONLY across kernel boundaries (no atomics, no polling).
__global__ __launch_bounds__(256, 1) void rnnt_step(
    const float* __restrict__ xp, const float* __restrict__ Gm,
    const float* __restrict__ Wo4, const float* __restrict__ Wh4,
    const float* __restrict__ Wp4,
    const float* __restrict__ b_out, const float* __restrict__ b_lstm,
    const float* __restrict__ b_pred, const int* __restrict__ out_len,
    float* __restrict__ cb, float* __restrict__ db, float* __restrict__ gb,
    ull* __restrict__ keys, int* __restrict__ rec, float* __restrict__ out,
    int L) {
    __shared__ __align__(16) float h_s[Hn];
    __shared__ __align__(16) float dec_s[Jn];
    __shared__ __align__(16) float f_s[Jn];
    __shared__ ull bk_s;

    const int w = blockIdx.x, tid = threadIdx.x;
    const int b = w & 31, m = w >> 5;
    const int ol = out_len[b];
    const float4* Wo4f = (const float4*)Wo4;
    const float4* Wh4f = (const float4*)Wh4;
    const float4* Wp4f = (const float4*)Wp4;
    const float4* h4 = (const float4*)h_s;
    const float4* f4 = (const float4*)f_s;

    int tnew, genN;
    bool doDec;
    if (L == 0) {
        // prologue: h0,c0 replicated; c0 slice store; rec[0]
        for (int r = tid; r < Hn; r += 256) {
            float c0 = sigmf(b_lstm[r]) * tanhf(b_lstm[2 * Hn + r]);
            float h0 = sigmf(b_lstm[3 * Hn + r]) * tanhf(c0);
            h_s[r] = h0;
            int lc = r - m * 40;
            if (lc >= 0 && lc < 40) cb[b * Hn + r] = c0;   // parity 0
        }
        if (m == 0 && tid == 0) {
            int* rn = rec + b * 4;                          // parity 0
            rn[0] = 0; rn[1] = 0; rn[2] = 0;
        }
        __syncthreads();
        tnew = 0; genN = 0; doDec = true;
    } else {
        // ---- decode step L-1 from keys/rec written by launch L-1 ----
        const int* rp = rec + ((L - 1) & 1) * Bn * 4 + b * 4;
        const int told = rp[0], sold = rp[1], len = rp[2];
        if (tid < 64) {
            ull k = 0;
            if (tid < 33) k = keys[((L - 1) & 1) * Bn * 40 + b * 40 + tid];
#pragma unroll
            for (int d = 1; d < 64; d <<= 1) {
                ull o = __shfl_xor(k, d, 64);
                if (o > k) k = o;
            }
            if (tid == 0) bk_s = k;
        }
        __syncthreads();
        const ull bk = bk_s;
        const int label = key_idx(bk);
        const bool active = told < ol;
        const bool emit = active && (label != Vn);
        int sym2 = emit ? sold + 1 : 0;
        const bool force = emit && (sym2 >= 2);
        const bool advance = (active && !emit) || force;
        tnew = told + (advance ? 1 : 0);
        sym2 = advance ? 0 : sym2;
        const int newlen = len + (emit ? 1 : 0);
        if (m == 0 && tid == 0) {
            out[(L - 1) * Bn + b] = emit ? (float)label : 1024.0f;
            out[Sn * Bn + (L - 1) * Bn + b] = active ? key_val(bk) : 0.0f;
            out[2 * Sn * Bn + (L - 1) * Bn + b] = (float)told;
            int* rn = rec + (L & 1) * Bn * 4 + b * 4;
            rn[0] = tnew; rn[1] = sym2; rn[2] = newlen;
            if (L == Sn) out[3 * Sn * Bn + b] = (float)newlen;
        }
        if (L == Sn) return;
        if (tnew >= ol) return;       // frozen: no phase 2 needed ever again
        genN = newlen;
        doDec = emit;
        if (emit) {
            // LSTM (replicated): h2 -> LDS; own c2 slice -> parity newlen&1
            const float* cv = cb + (len & 1) * Bn * Hn + b * Hn;
            float* cn = cb + (newlen & 1) * Bn * Hn + b * Hn;
            const float* gg = gb + (len & 1) * Bn * G4n + b * G4n;
            const float* gE = Gm + (size_t)label * G4n;
            {
                const int r = tid;
                float xi = gg[r] + gE[r];
                float xf = gg[Hn + r] + gE[Hn + r];
                float xg = gg[2 * Hn + r] + gE[2 * Hn + r];
                float xo = gg[3 * Hn + r] + gE[3 * Hn + r];
                float c2 = sigmf(xf) * cv[r] + sigmf(xi) * tanhf(xg);
                float h2 = sigmf(xo) * tanhf(c2);
                h_s[r] = h2;
                int lc = r - m * 40;
                if (lc >= 0 && lc < 40) cn[r] = c2;
            }
            if (tid < 64) {
                const int r = 256 + tid;
                float xi = gg[r] + gE[r];
                float xf = gg[Hn + r] + gE[Hn + r];
                float xg = gg[2 * Hn + r] + gE[2 * Hn + r];
                float xo = gg[3 * Hn + r] + gE[3 * Hn + r];
                float c2 = sigmf(xf) * cv[r] + sigmf(xi) * tanhf(xg);
                float h2 = sigmf(xo) * tanhf(c2);
                h_s[r] = h2;
                int lc = r - m * 40;
                if (lc >= 0 && lc < 40) cn[r] = c2;
            }
            __syncthreads();   // h_s complete
        } else {
            // blank: dec unchanged -> reload from parity buffer
            dec_s[tid] = db[(len & 1) * Bn * Jn + b * Jn + tid];
            if (tid < 64) dec_s[256 + tid] = db[(len & 1) * Bn * Jn + b * Jn + 256 + tid];
        }
    }
    // ---- phase 2: dec-full (if h changed) + gates slice + f + logits slice ----
    if (doDec) {
        float* dn = db + (genN & 1) * Bn * Jn + b * Jn;
        {
            const int c = tid;
            float ax = 0.f, ay = 0.f, az = 0.f, aw = 0.f;
#pragma unroll 20
            for (int k4 = 0; k4 < 80; ++k4) {
                float4 wv = Wp4f[(size_t)k4 * Jn + c];
                float4 hv = h4[k4];
                ax += wv.x * hv.x; ay += wv.y * hv.y;
                az += wv.z * hv.z; aw += wv.w * hv.w;
            }
            float d = b_pred[c] + ax + ay + az + aw;
            dec_s[c] = d;
            int lc = c - m * 40;
            if (lc >= 0 && lc < 40) dn[c] = d;
        }
        if (tid < 64) {
            const int c = 256 + tid;
            float ax = 0.f, ay = 0.f, az = 0.f, aw = 0.f;
#pragma unroll 20
            for (int k4 = 0; k4 < 80; ++k4) {
                float4 wv = Wp4f[(size_t)k4 * Jn + c];
                float4 hv = h4[k4];
                ax += wv.x * hv.x; ay += wv.y * hv.y;
                az += wv.z * hv.z; aw += wv.w * hv.w;
            }
            float d = b_pred[c] + ax + ay + az + aw;
            dec_s[c] = d;
            int lc = c - m * 40;
            if (lc >= 0 && lc < 40) dn[c] = d;
        }
        if (tid < 160) {
            const int c = m * 160 + tid;
            float ax = 0.f, ay = 0.f, az = 0.f, aw = 0.f;
#pragma unroll 20
            for (int k4 = 0; k4 < 80; ++k4) {
                float4 wv = Wh4f[(size_t)k4 * G4n + c];
                float4 hv = h4[k4];
                ax += wv.x * hv.x; ay += wv.y * hv.y;
                az += wv.z * hv.z; aw += wv.w * hv.w;
            }
            gb[(genN & 1) * Bn * G4n + b * G4n + c] = ax + ay + az + aw;
        }
    }
    // ---- f = relu(xp[tnew] + dec) (per-thread indices match dec_s writes) ----
    {
        const int tc = tnew < (Tn - 1) ? tnew : (Tn - 1);
        const float* xr = xp + (size_t)(b * Tn + tc) * Jn;
        f_s[tid] = fmaxf(xr[tid] + dec_s[tid], 0.0f);
        if (tid < 64) f_s[256 + tid] = fmaxf(xr[256 + tid] + dec_s[256 + tid], 0.0f);
    }
    __syncthreads();   // f_s full
    // ---- logits slice: 2 threads/col, 128 cols; per-wave key -> keys[L&1] ----
    {
        const int cl = tid >> 1, kh = tid & 1;
        const int c = m * 128 + cl;
        float ax = 0.f, ay = 0.f, az = 0.f, aw = 0.f;
#pragma unroll 10
        for (int k4 = kh * 40; k4 < kh * 40 + 40; ++k4) {
            float4 wv = Wo4f[(size_t)k4 * WO4S + c];
            float4 fv = f4[k4];
            ax += wv.x * fv.x; ay += wv.y * fv.y;
            az += wv.z * fv.z; aw += wv.w * fv.w;
        }
        float part = ax + ay + az + aw;
        part += __shfl_xor(part, 1, 64);
        ull key = pack_key(part + b_out[c], c);
#pragma unroll
        for (int d = 1; d < 64; d <<= 1) {
            ull o = __shfl_xor(key, d, 64);
            if (o > key) key = o;
        }
        if ((tid & 63) == 0) keys[(L & 1) * Bn * 40 + b * 40 + m * 4 + (tid >> 6)] = key;
    }
    if (m == 7 && tid >= 192) {   // blank column 1024
        const int l = tid - 192;
        float4 wv = Wo4f[(size_t)l * WO4S + Vn];
        float4 fv = f4[l];
        float p = wv.x * fv.x + wv.y * fv.y + wv.z * fv.z + wv.w * fv.w;
        if (l < 16) {
            float4 wv2 = Wo4f[(size_t)(64 + l) * WO4S + Vn];
            float4 fv2 = f4[64 + l];
            p += wv2.x * fv2.x + wv2.y * fv2.y + wv2.z * fv2.z + wv2.w * fv2.w;
        }
#pragma unroll
        for (int d = 1; d < 64; d <<= 1) p += __shfl_xor(p, d, 64);
        if (l == 0) keys[(L & 1) * Bn * 40 + b * 40 + 32] = pack_key(p + b_out[Vn], Vn);
    }
}

extern "C" void kernel_launch(void* const* d_in, const int* in_sizes, int n_in,
                              void* d_out, int out_size, void* d_ws, size_t ws_size,
                              hipStream_t stream) {
    (void)in_sizes; (void)n_in; (void)out_size; (void)ws_size;
    const float* x      = (const float*)d_in[0];
    const int*   outlen = (const int*)d_in[1];
    const float* W_enc  = (const float*)d_in[2];
    const float* b_enc  = (const float*)d_in[3];
    const float* Emb    = (const float*)d_in[4];
    const float* W_ih   = (const float*)d_in[5];
    const float* W_hh   = (const float*)d_in[6];
    const float* b_lstm = (const float*)d_in[7];
    const float* W_pred = (const float*)d_in[8];
    const float* b_pred = (const float*)d_in[9];
    const float* W_out  = (const float*)d_in[10];
    const float* b_out  = (const float*)d_in[11];

    float* ws  = (float*)d_ws;
    float* xp  = ws + OFF_XP;
    float* Gm  = ws + OFF_G;
    float* Wo4 = ws + OFF_WO4;
    float* Wh4 = ws + OFF_WH4;
    float* Wp4 = ws + OFF_WP4;
    float* cb  = ws + OFF_CB;
    float* db  = ws + OFF_DEC;
    float* gb  = ws + OFF_GB;
    ull*   keys = (ull*)(ws + OFF_KEY);
    int*   rec  = (int*)(ws + OFF_REC);

    gemm_bias<<<dim3(5, 32), 256, 0, stream>>>(x, W_enc, b_enc, xp, Bn * Tn, Jn, 1024);
    gemm_bias<<<dim3(20, 16), 256, 0, stream>>>(Emb, W_ih, b_lstm, Gm, Vn, G4n, Hn);
    repack_wout4<<<80, 256, 0, stream>>>(W_out, Wo4);
    repack_whh4<<<80, 256, 0, stream>>>(W_hh, Wh4);
    repack_wpred4<<<80, 256, 0, stream>>>(W_pred, Wp4);

    for (int L = 0; L <= Sn; ++L)
        rnnt_step<<<256, 256, 0, stream>>>(xp, Gm, Wo4, Wh4, Wp4,
                                           b_out, b_lstm, b_pred, outlen,
                                           cb, db, gb, keys, rec,
                                           (float*)d_out, L);
}

// Round 14
// 2036.224 us; speedup vs baseline: 2.4529x; 1.0315x over previous
//
#include <hip/hip_runtime.h>
#include <math.h>

typedef unsigned long long ull;

constexpr int Bn = 32, Tn = 64, Hn = 320, Jn = 320, Vn = 1024, Sn = 128;
constexpr int G4n = 1280, VP1 = 1025, WO4S = 1028;

// workspace layout (float units) -- ~11.8 MB
constexpr int OFF_XP  = 0;                        // 32*64*320
constexpr int OFF_G   = OFF_XP + Bn*Tn*Jn;        // 1024*1280
constexpr int OFF_WO4 = OFF_G + Vn*G4n;           // 80*1028*4
constexpr int OFF_WH4 = OFF_WO4 + 80*WO4S*4;      // 80*1280*4
constexpr int OFF_WP4 = OFF_WH4 + 80*G4n*4;       // 80*320*4
constexpr int OFF_CB  = OFF_WP4 + 80*Jn*4;        // 2*32*320 c (emit-parity)
constexpr int OFF_DEC = OFF_CB + 2*Bn*Hn;         // 2*32*320 dec (emit-parity)
constexpr int OFF_GB  = OFF_DEC + 2*Bn*Jn;        // 2*32*1280 gates (emit-parity)
constexpr int OFF_KEY = OFF_GB + 2*Bn*G4n;        // 2*32*40 ull (step-parity)
constexpr int OFF_REC = OFF_KEY + 2*Bn*40*2;      // 2*32*4 int (step-parity)

__device__ __forceinline__ float sigmf(float x) { return 1.0f / (1.0f + expf(-x)); }

// monotonic (value,idx) pack: bigger float -> bigger key; tie -> smaller idx wins
__device__ __forceinline__ ull pack_key(float v, int idx) {
    unsigned u = __float_as_uint(v);
    u = (u & 0x80000000u) ? ~u : (u | 0x80000000u);
    return ((ull)u << 32) | (unsigned)(0x7FFFFFFF - idx);
}
__device__ __forceinline__ float key_val(ull k) {
    unsigned u = (unsigned)(k >> 32);
    return __uint_as_float((u & 0x80000000u) ? (u & 0x7FFFFFFFu) : ~u);
}
__device__ __forceinline__ int key_idx(ull k) { return 0x7FFFFFFF - (int)(k & 0xFFFFFFFFu); }

// ---------------- tiled f32 GEMM tile (device) ----------------
__device__ __forceinline__ void gemm_tile(const float* __restrict__ A,
                                          const float* __restrict__ Bm,
                                          const float* __restrict__ bias,
                                          float* __restrict__ C,
                                          int M, int N, int K, int bx, int by,
                                          float (*As)[65], float (*Bs)[65]) {
    const int tx = threadIdx.x & 15, ty = threadIdx.x >> 4;
    const int n0 = bx * 64, m0 = by * 64;
    float acc[4][4] = {};
    for (int k0 = 0; k0 < K; k0 += 16) {
        for (int i = threadIdx.x; i < 1024; i += 256) {
            int mm = i >> 4, kk = i & 15;
            As[kk][mm] = A[(m0 + mm) * K + k0 + kk];
            int kk2 = i >> 6, nn = i & 63;
            Bs[kk2][nn] = Bm[(k0 + kk2) * N + n0 + nn];
        }
        __syncthreads();
#pragma unroll
        for (int kk = 0; kk < 16; ++kk) {
            float av[4], bv[4];
#pragma unroll
            for (int r = 0; r < 4; ++r) { av[r] = As[kk][ty * 4 + r]; bv[r] = Bs[kk][tx * 4 + r]; }
#pragma unroll
            for (int i2 = 0; i2 < 4; ++i2)
#pragma unroll
                for (int j2 = 0; j2 < 4; ++j2) acc[i2][j2] += av[i2] * bv[j2];
        }
        __syncthreads();
    }
#pragma unroll
    for (int i2 = 0; i2 < 4; ++i2)
#pragma unroll
        for (int j2 = 0; j2 < 4; ++j2)
            C[(m0 + ty * 4 + i2) * N + n0 + tx * 4 + j2] = acc[i2][j2] + bias[n0 + tx * 4 + j2];
}

// ---------------- fused preamble: both GEMMs + 3 repacks in ONE launch ----------------
__global__ __launch_bounds__(256) void preamble(
    const float* __restrict__ x, const float* __restrict__ W_enc,
    const float* __restrict__ b_enc, const float* __restrict__ Emb,
    const float* __restrict__ W_ih, const float* __restrict__ b_lstm,
    const float* __restrict__ W_hh, const float* __restrict__ W_pred,
    const float* __restrict__ W_out,
    float* __restrict__ xp, float* __restrict__ Gm,
    float* __restrict__ Wo4, float* __restrict__ Wh4, float* __restrict__ Wp4) {
    __shared__ float As[16][65];
    __shared__ float Bs[16][65];
    const int blk = blockIdx.x;
    if (blk < 160) {
        gemm_tile(x, W_enc, b_enc, xp, Bn * Tn, Jn, 1024, blk % 5, blk / 5, As, Bs);
    } else if (blk < 480) {
        const int t = blk - 160;
        gemm_tile(Emb, W_ih, b_lstm, Gm, Vn, G4n, Hn, t % 20, t / 20, As, Bs);
    } else if (blk < 560) {
        const int k4 = blk - 480;
        for (int c = threadIdx.x; c < VP1; c += 256) {
            float4 v;
            v.x = W_out[(k4 * 4 + 0) * VP1 + c];
            v.y = W_out[(k4 * 4 + 1) * VP1 + c];
            v.z = W_out[(k4 * 4 + 2) * VP1 + c];
            v.w = W_out[(k4 * 4 + 3) * VP1 + c];
            ((float4*)Wo4)[(size_t)k4 * WO4S + c] = v;
        }
    } else if (blk < 640) {
        const int k4 = blk - 560;
        for (int c = threadIdx.x; c < G4n; c += 256) {
            float4 v;
            v.x = W_hh[(k4 * 4 + 0) * G4n + c];
            v.y = W_hh[(k4 * 4 + 1) * G4n + c];
            v.z = W_hh[(k4 * 4 + 2) * G4n + c];
            v.w = W_hh[(k4 * 4 + 3) * G4n + c];
            ((float4*)Wh4)[(size_t)k4 * G4n + c] = v;
        }
    } else {
        const int k4 = blk - 640;
        for (int c = threadIdx.x; c < Jn; c += 256) {
            float4 v;
            v.x = W_pred[(k4 * 4 + 0) * Jn + c];
            v.y = W_pred[(k4 * 4 + 1) * Jn + c];
            v.z = W_pred[(k4 * 4 + 2) * Jn + c];
            v.w = W_pred[(k4 * 4 + 3) * Jn + c];
            ((float4*)Wp4)[(size_t)k4 * Jn + c] = v;
        }
    }
}

// ---------------- one decode step per launch; 8 WGs per batch element ----------------
// Cross-WG data flows ONLY across kernel boundaries. 320 threads: one row/col each.
__global__ __launch_bounds__(320, 1) void rnnt_step(
    const float* __restrict__ xp, const float* __restrict__ Gm,
    const float* __restrict__ Wo4, const float* __restrict__ Wh4,
    const float* __restrict__ Wp4,
    const float* __restrict__ b_out, const float* __restrict__ b_lstm,
    const float* __restrict__ b_pred, const int* __restrict__ out_len,
    float* __restrict__ cb, float* __restrict__ db, float* __restrict__ gb,
    ull* __restrict__ keys, int* __restrict__ rec, float* __restrict__ out,
    int L) {
    __shared__ __align__(16) float h_s[Hn];
    __shared__ __align__(16) float dec_s[Jn];
    __shared__ __align__(16) float f_s[Jn];
    __shared__ ull bk_s;

    const int w = blockIdx.x, tid = threadIdx.x;
    const int b = w & 31, m = w >> 5;
    const int ol = out_len[b];
    const float4* Wo4f = (const float4*)Wo4;
    const float4* Wh4f = (const float4*)Wh4;
    const float4* Wp4f = (const float4*)Wp4;
    const float4* h4 = (const float4*)h_s;
    const float4* f4 = (const float4*)f_s;

    int tnew, genN;
    bool doDec;
    if (L == 0) {
        // prologue: h0,c0 (one row per thread); c0 slice store; rec[parity 0]
        {
            const int r = tid;
            float c0 = sigmf(b_lstm[r]) * tanhf(b_lstm[2 * Hn + r]);
            float h0 = sigmf(b_lstm[3 * Hn + r]) * tanhf(c0);
            h_s[r] = h0;
            int lc = r - m * 40;
            if (lc >= 0 && lc < 40) cb[b * Hn + r] = c0;
        }
        if (m == 0 && tid == 0) {
            int* rn = rec + b * 4;
            rn[0] = 0; rn[1] = 0; rn[2] = 0;
        }
        __syncthreads();
        tnew = 0; genN = 0; doDec = true;
    } else {
        const int* rp = rec + ((L - 1) & 1) * Bn * 4 + b * 4;
        const int told = rp[0], sold = rp[1], len = rp[2];
        // early LSTM-input prefetch into registers (overlaps key load+reduce);
        // only the Gm[label] row must wait for the argmax result.
        const float* gq = gb + (size_t)((len & 1) * Bn + b) * G4n;
        const float* cv = cb + (size_t)((len & 1) * Bn + b) * Hn;
        float g0 = gq[tid], g1 = gq[Hn + tid], g2 = gq[2 * Hn + tid], g3 = gq[3 * Hn + tid];
        float crv = cv[tid];
        asm volatile("" ::: "memory");   // pin the prefetch issue point (wait happens at use)
        if (tid < 64) {
            ull k = 0;
            if (tid < 33) k = keys[((L - 1) & 1) * Bn * 40 + b * 40 + tid];
#pragma unroll
            for (int d = 1; d < 64; d <<= 1) {
                ull o = __shfl_xor(k, d, 64);
                if (o > k) k = o;
            }
            if (tid == 0) bk_s = k;
        }
        __syncthreads();
        const ull bk = bk_s;
        const int label = key_idx(bk);
        const bool active = told < ol;
        const bool emit = active && (label != Vn);
        int sym2 = emit ? sold + 1 : 0;
        const bool force = emit && (sym2 >= 2);
        const bool advance = (active && !emit) || force;
        tnew = told + (advance ? 1 : 0);
        sym2 = advance ? 0 : sym2;
        const int newlen = len + (emit ? 1 : 0);
        if (m == 0 && tid == 0) {
            out[(L - 1) * Bn + b] = emit ? (float)label : 1024.0f;
            out[Sn * Bn + (L - 1) * Bn + b] = active ? key_val(bk) : 0.0f;
            out[2 * Sn * Bn + (L - 1) * Bn + b] = (float)told;
            int* rn = rec + (L & 1) * Bn * 4 + b * 4;
            rn[0] = tnew; rn[1] = sym2; rn[2] = newlen;
            if (L == Sn) out[3 * Sn * Bn + b] = (float)newlen;
        }
        if (L == Sn) return;
        if (tnew >= ol) return;       // frozen forever: later launches see active=false
        genN = newlen;
        doDec = emit;
        if (emit) {
            const float* gE = Gm + (size_t)label * G4n;
            float xi = g0 + gE[tid];
            float xf = g1 + gE[Hn + tid];
            float xg = g2 + gE[2 * Hn + tid];
            float xo = g3 + gE[3 * Hn + tid];
            float c2 = sigmf(xf) * crv + sigmf(xi) * tanhf(xg);
            float h2 = sigmf(xo) * tanhf(c2);
            h_s[tid] = h2;
            int lc = tid - m * 40;
            if (lc >= 0 && lc < 40)
                cb[(size_t)((newlen & 1) * Bn + b) * Hn + tid] = c2;
        } else {
            dec_s[tid] = db[(size_t)((len & 1) * Bn + b) * Jn + tid];
        }
        __syncthreads();   // h_s (emit) or dec_s (blank) ready
    }
    // ---- phase 2: dec-full (one col/thread) + gates slice (tid<160) ----
    if (doDec) {
        float* dn = db + (size_t)((genN & 1) * Bn + b) * Jn;
        {
            const int c = tid;
            float ax = 0.f, ay = 0.f, az = 0.f, aw = 0.f;
#pragma unroll 20
            for (int k4 = 0; k4 < 80; ++k4) {
                float4 wv = Wp4f[(size_t)k4 * Jn + c];
                float4 hv = h4[k4];
                ax += wv.x * hv.x; ay += wv.y * hv.y;
                az += wv.z * hv.z; aw += wv.w * hv.w;
            }
            float d = b_pred[c] + ax + ay + az + aw;
            dec_s[c] = d;
            int lc = c - m * 40;
            if (lc >= 0 && lc < 40) dn[c] = d;
        }
        if (tid < 160) {
            const int c = m * 160 + tid;
            float ax = 0.f, ay = 0.f, az = 0.f, aw = 0.f;
#pragma unroll 20
            for (int k4 = 0; k4 < 80; ++k4) {
                float4 wv = Wh4f[(size_t)k4 * G4n + c];
                float4 hv = h4[k4];
                ax += wv.x * hv.x; ay += wv.y * hv.y;
                az += wv.z * hv.z; aw += wv.w * hv.w;
            }
            gb[(size_t)((genN & 1) * Bn + b) * G4n + c] = ax + ay + az + aw;
        }
    }
    __syncthreads();   // dec_s full
    // ---- f = relu(xp[tnew] + dec) ----
    {
        const int tc = tnew < (Tn - 1) ? tnew : (Tn - 1);
        const float* xr = xp + (size_t)(b * Tn + tc) * Jn;
        f_s[tid] = fmaxf(xr[tid] + dec_s[tid], 0.0f);
    }
    __syncthreads();   // f_s full
    // ---- logits slice: 2 threads/col on waves 0-3; blank col on wave 4 (m==7) ----
    if (tid < 256) {
        const int cl = tid >> 1, kh = tid & 1;
        const int c = m * 128 + cl;
        float ax = 0.f, ay = 0.f, az = 0.f, aw = 0.f;
#pragma unroll 10
        for (int k4 = kh * 40; k4 < kh * 40 + 40; ++k4) {
            float4 wv = Wo4f[(size_t)k4 * WO4S + c];
            float4 fv = f4[k4];
            ax += wv.x * fv.x; ay += wv.y * fv.y;
            az += wv.z * fv.z; aw += wv.w * fv.w;
        }
        float part = ax + ay + az + aw;
        part += __shfl_xor(part, 1, 64);
        ull key = pack_key(part + b_out[c], c);
#pragma unroll
        for (int d = 1; d < 64; d <<= 1) {
            ull o = __shfl_xor(key, d, 64);
            if (o > key) key = o;
        }
        if ((tid & 63) == 0)
            keys[(L & 1) * Bn * 40 + b * 40 + m * 4 + (tid >> 6)] = key;
    } else if (m == 7) {
        const int l = tid - 256;   // wave 4: blank column 1024
        float4 wv = Wo4f[(size_t)l * WO4S + Vn];
        float4 fv = f4[l];
        float p = wv.x * fv.x + wv.y * fv.y + wv.z * fv.z + wv.w * fv.w;
        if (l < 16) {
            float4 wv2 = Wo4f[(size_t)(64 + l) * WO4S + Vn];
            float4 fv2 = f4[64 + l];
            p += wv2.x * fv2.x + wv2.y * fv2.y + wv2.z * fv2.z + wv2.w * fv2.w;
        }
#pragma unroll
        for (int d = 1; d < 64; d <<= 1) p += __shfl_xor(p, d, 64);
        if (l == 0) keys[(L & 1) * Bn * 40 + b * 40 + 32] = pack_key(p + b_out[Vn], Vn);
    }
}

extern "C" void kernel_launch(void* const* d_in, const int* in_sizes, int n_in,
                              void* d_out, int out_size, void* d_ws, size_t ws_size,
                              hipStream_t stream) {
    (void)in_sizes; (void)n_in; (void)out_size; (void)ws_size;
    const float* x      = (const float*)d_in[0];
    const int*   outlen = (const int*)d_in[1];
    const float* W_enc  = (const float*)d_in[2];
    const float* b_enc  = (const float*)d_in[3];
    const float* Emb    = (const float*)d_in[4];
    const float* W_ih   = (const float*)d_in[5];
    const float* W_hh   = (const float*)d_in[6];
    const float* b_lstm = (const float*)d_in[7];
    const float* W_pred = (const float*)d_in[8];
    const float* b_pred = (const float*)d_in[9];
    const float* W_out  = (const float*)d_in[10];
    const float* b_out  = (const float*)d_in[11];

    float* ws  = (float*)d_ws;
    float* xp  = ws + OFF_XP;
    float* Gm  = ws + OFF_G;
    float* Wo4 = ws + OFF_WO4;
    float* Wh4 = ws + OFF_WH4;
    float* Wp4 = ws + OFF_WP4;
    float* cb  = ws + OFF_CB;
    float* db  = ws + OFF_DEC;
    float* gb  = ws + OFF_GB;
    ull*   keys = (ull*)(ws + OFF_KEY);
    int*   rec  = (int*)(ws + OFF_REC);

    preamble<<<720, 256, 0, stream>>>(x, W_enc, b_enc, Emb, W_ih, b_lstm,
                                      W_hh, W_pred, W_out,
                                      xp, Gm, Wo4, Wh4, Wp4);

    for (int L = 0; L <= Sn; ++L)
        rnnt_step<<<256, 320, 0, stream>>>(xp, Gm, Wo4, Wh4, Wp4,
                                           b_out, b_lstm, b_pred, outlen,
                                           cb, db, gb, keys, rec,
                                           (float*)d_out, L);
}

// Round 15
// 1938.583 us; speedup vs baseline: 2.5765x; 1.0504x over previous
//
#include <hip/hip_runtime.h>
#include <math.h>

typedef unsigned long long ull;

constexpr int Bn = 32, Tn = 64, Hn = 320, Jn = 320, Vn = 1024, Sn = 128;
constexpr int G4n = 1280, VP1 = 1025, WO4S = 1028;

// workspace layout (float units) -- ~13.9 MB
constexpr int OFF_XP  = 0;                        // 32*64*320
constexpr int OFF_G   = OFF_XP + Bn*Tn*Jn;        // 1024*1280
constexpr int OFF_WO4 = OFF_G + Vn*G4n;           // 80*1028*4
constexpr int OFF_WH4 = OFF_WO4 + 80*WO4S*4;      // 80*1280*4
constexpr int OFF_WP4 = OFF_WH4 + 80*G4n*4;       // 80*320*4
constexpr int OFF_CB  = OFF_WP4 + 80*Jn*4;        // 2*32*320 c (emit-parity)
constexpr int OFF_DEC = OFF_CB + 2*Bn*Hn;         // 2*32*320 dec (emit-parity)
constexpr int OFF_GB  = OFF_DEC + 2*Bn*Jn;        // 2*32*1280 gates (emit-parity)
constexpr int OFF_PB  = OFF_GB + 2*Bn*G4n;        // 2*32*8*1028 partial logits (step-parity)
constexpr int OFF_REC = OFF_PB + 2*Bn*8*1028;     // 2*32*4 int (step-parity)

__device__ __forceinline__ float sigmf(float x) { return 1.0f / (1.0f + expf(-x)); }

// monotonic (value,idx) pack: bigger float -> bigger key; tie -> smaller idx wins
__device__ __forceinline__ ull pack_key(float v, int idx) {
    unsigned u = __float_as_uint(v);
    u = (u & 0x80000000u) ? ~u : (u | 0x80000000u);
    return ((ull)u << 32) | (unsigned)(0x7FFFFFFF - idx);
}
__device__ __forceinline__ float key_val(ull k) {
    unsigned u = (unsigned)(k >> 32);
    return __uint_as_float((u & 0x80000000u) ? (u & 0x7FFFFFFFu) : ~u);
}
__device__ __forceinline__ int key_idx(ull k) { return 0x7FFFFFFF - (int)(k & 0xFFFFFFFFu); }

// ---------------- tiled f32 GEMM tile (device); As stride 68 = conflict-free ----------------
__device__ __forceinline__ void gemm_tile(const float* __restrict__ A,
                                          const float* __restrict__ Bm,
                                          const float* __restrict__ bias,
                                          float* __restrict__ C,
                                          int M, int N, int K, int bx, int by,
                                          float (*As)[68], float (*Bs)[65]) {
    const int tx = threadIdx.x & 15, ty = threadIdx.x >> 4;
    const int n0 = bx * 64, m0 = by * 64;
    float acc[4][4] = {};
    for (int k0 = 0; k0 < K; k0 += 16) {
        for (int i = threadIdx.x; i < 1024; i += 256) {
            int mm = i >> 4, kk = i & 15;
            As[kk][mm] = A[(m0 + mm) * K + k0 + kk];
            int kk2 = i >> 6, nn = i & 63;
            Bs[kk2][nn] = Bm[(k0 + kk2) * N + n0 + nn];
        }
        __syncthreads();
#pragma unroll
        for (int kk = 0; kk < 16; ++kk) {
            float av[4], bv[4];
#pragma unroll
            for (int r = 0; r < 4; ++r) { av[r] = As[kk][ty * 4 + r]; bv[r] = Bs[kk][tx * 4 + r]; }
#pragma unroll
            for (int i2 = 0; i2 < 4; ++i2)
#pragma unroll
                for (int j2 = 0; j2 < 4; ++j2) acc[i2][j2] += av[i2] * bv[j2];
        }
        __syncthreads();
    }
#pragma unroll
    for (int i2 = 0; i2 < 4; ++i2)
#pragma unroll
        for (int j2 = 0; j2 < 4; ++j2)
            C[(m0 + ty * 4 + i2) * N + n0 + tx * 4 + j2] = acc[i2][j2] + bias[n0 + tx * 4 + j2];
}

// ---------------- fused preamble: both GEMMs + 3 repacks in ONE launch ----------------
__global__ __launch_bounds__(256) void preamble(
    const float* __restrict__ x, const float* __restrict__ W_enc,
    const float* __restrict__ b_enc, const float* __restrict__ Emb,
    const float* __restrict__ W_ih, const float* __restrict__ b_lstm,
    const float* __restrict__ W_hh, const float* __restrict__ W_pred,
    const float* __restrict__ W_out,
    float* __restrict__ xp, float* __restrict__ Gm,
    float* __restrict__ Wo4, float* __restrict__ Wh4, float* __restrict__ Wp4) {
    __shared__ float As[16][68];
    __shared__ float Bs[16][65];
    const int blk = blockIdx.x;
    if (blk < 160) {
        gemm_tile(x, W_enc, b_enc, xp, Bn * Tn, Jn, 1024, blk % 5, blk / 5, As, Bs);
    } else if (blk < 480) {
        const int t = blk - 160;
        gemm_tile(Emb, W_ih, b_lstm, Gm, Vn, G4n, Hn, t % 20, t / 20, As, Bs);
    } else if (blk < 560) {
        const int k4 = blk - 480;
        for (int c = threadIdx.x; c < VP1; c += 256) {
            float4 v;
            v.x = W_out[(k4 * 4 + 0) * VP1 + c];
            v.y = W_out[(k4 * 4 + 1) * VP1 + c];
            v.z = W_out[(k4 * 4 + 2) * VP1 + c];
            v.w = W_out[(k4 * 4 + 3) * VP1 + c];
            ((float4*)Wo4)[(size_t)k4 * WO4S + c] = v;
        }
    } else if (blk < 640) {
        const int k4 = blk - 560;
        for (int c = threadIdx.x; c < G4n; c += 256) {
            float4 v;
            v.x = W_hh[(k4 * 4 + 0) * G4n + c];
            v.y = W_hh[(k4 * 4 + 1) * G4n + c];
            v.z = W_hh[(k4 * 4 + 2) * G4n + c];
            v.w = W_hh[(k4 * 4 + 3) * G4n + c];
            ((float4*)Wh4)[(size_t)k4 * G4n + c] = v;
        }
    } else {
        const int k4 = blk - 640;
        for (int c = threadIdx.x; c < Jn; c += 256) {
            float4 v;
            v.x = W_pred[(k4 * 4 + 0) * Jn + c];
            v.y = W_pred[(k4 * 4 + 1) * Jn + c];
            v.z = W_pred[(k4 * 4 + 2) * Jn + c];
            v.w = W_pred[(k4 * 4 + 3) * Jn + c];
            ((float4*)Wp4)[(size_t)k4 * Jn + c] = v;
        }
    }
}

// ---------------- one decode step per launch; 8 WGs per batch element ----------------
// K-sliced partial logits: NO key exchange, NO dec replication. Every member
// reduces the previous launch's 8 partial-logit rows to decode identically.
__global__ __launch_bounds__(320, 1) void rnnt_step(
    const float* __restrict__ xp, const float* __restrict__ Gm,
    const float* __restrict__ Wo4, const float* __restrict__ Wh4,
    const float* __restrict__ Wp4,
    const float* __restrict__ b_out, const float* __restrict__ b_lstm,
    const float* __restrict__ b_pred, const int* __restrict__ out_len,
    float* __restrict__ cb, float* __restrict__ db, float* __restrict__ gb,
    float* __restrict__ pb, int* __restrict__ rec, float* __restrict__ out,
    int L) {
    __shared__ __align__(16) float h_s[Hn];
    __shared__ __align__(16) float f_s[48];
    __shared__ float dec_s[40];
    __shared__ ull wk_s[5];

    const int w = blockIdx.x, tid = threadIdx.x;
    const int b = w & 31, m = w >> 5;
    const int ol = out_len[b];
    const float4* Wo4f = (const float4*)Wo4;
    const float4* Wh4f = (const float4*)Wh4;
    const float4* Wp4f = (const float4*)Wp4;
    const float4* h4 = (const float4*)h_s;

    int tnew, genN;
    bool doDec;
    if (L == 0) {
        // prologue: h0,c0 (one row per thread); c0 slice store; rec[parity 0]
        float c0 = sigmf(b_lstm[tid]) * tanhf(b_lstm[2 * Hn + tid]);
        float h0 = sigmf(b_lstm[3 * Hn + tid]) * tanhf(c0);
        h_s[tid] = h0;
        int lc = tid - m * 40;
        if (lc >= 0 && lc < 40) cb[b * Hn + tid] = c0;
        if (m == 0 && tid == 0) {
            int* rn = rec + b * 4;
            rn[0] = 0; rn[1] = 0; rn[2] = 0;
        }
        tnew = 0; genN = 0; doDec = true;
        __syncthreads();
    } else {
        const int* rp = rec + ((L - 1) & 1) * Bn * 4 + b * 4;
        const int told = rp[0], sold = rp[1], len = rp[2];
        // prefetch LSTM inputs (overlap with partial-logit reduce)
        const float* gq = gb + (size_t)((len & 1) * Bn + b) * G4n;
        const float* cv = cb + (size_t)((len & 1) * Bn + b) * Hn;
        float g0 = gq[tid], g1 = gq[Hn + tid], g2 = gq[2 * Hn + tid], g3 = gq[3 * Hn + tid];
        float crv = cv[tid];
        asm volatile("" ::: "memory");
        // ---- replicated decode: sum 8 partial rows, argmax ----
        const float* pp = pb + (size_t)(((L - 1) & 1) * Bn + b) * 8 * 1028;
        ull key = 0;
        for (int c = tid; c < VP1; c += 320) {
            float sv = b_out[c];
#pragma unroll
            for (int mm = 0; mm < 8; ++mm) sv += pp[mm * 1028 + c];
            ull k2 = pack_key(sv, c);
            if (k2 > key) key = k2;
        }
#pragma unroll
        for (int d = 1; d < 64; d <<= 1) {
            ull o = __shfl_xor(key, d, 64);
            if (o > key) key = o;
        }
        if ((tid & 63) == 0) wk_s[tid >> 6] = key;
        __syncthreads();
        ull bk = wk_s[0];
#pragma unroll
        for (int i = 1; i < 5; ++i) if (wk_s[i] > bk) bk = wk_s[i];
        const int label = key_idx(bk);
        const bool active = told < ol;
        const bool emit = active && (label != Vn);
        int sym2 = emit ? sold + 1 : 0;
        const bool force = emit && (sym2 >= 2);
        const bool advance = (active && !emit) || force;
        tnew = told + (advance ? 1 : 0);
        sym2 = advance ? 0 : sym2;
        const int newlen = len + (emit ? 1 : 0);
        if (m == 0 && tid == 0) {
            out[(L - 1) * Bn + b] = emit ? (float)label : 1024.0f;
            out[Sn * Bn + (L - 1) * Bn + b] = active ? key_val(bk) : 0.0f;
            out[2 * Sn * Bn + (L - 1) * Bn + b] = (float)told;
            int* rn = rec + (L & 1) * Bn * 4 + b * 4;
            rn[0] = tnew; rn[1] = sym2; rn[2] = newlen;
            if (L == Sn) out[3 * Sn * Bn + b] = (float)newlen;
        }
        if (L == Sn) return;
        if (tnew >= ol) return;   // frozen: later launches still write outputs above
        genN = newlen;
        doDec = emit;
        if (emit) {
            const float* gE = Gm + (size_t)label * G4n;
            float xi = g0 + gE[tid];
            float xf = g1 + gE[Hn + tid];
            float xg = g2 + gE[2 * Hn + tid];
            float xo = g3 + gE[3 * Hn + tid];
            float c2 = sigmf(xf) * crv + sigmf(xi) * tanhf(xg);
            float h2 = sigmf(xo) * tanhf(c2);
            h_s[tid] = h2;
            int lc = tid - m * 40;
            if (lc >= 0 && lc < 40)
                cb[(size_t)((newlen & 1) * Bn + b) * Hn + tid] = c2;
        } else {
            if (tid < 40)
                dec_s[tid] = db[(size_t)((len & 1) * Bn + b) * Jn + m * 40 + tid];
        }
        __syncthreads();   // h_s (emit) / dec_s (blank) ready
    }
    // ---- phase 2 (h changed): gates slice (160 thr) + dec slice (40 thr) ----
    if (doDec) {
        if (tid < 160) {
            const int c = m * 160 + tid;
            float ax = 0.f, ay = 0.f, az = 0.f, aw = 0.f;
#pragma unroll 20
            for (int k4 = 0; k4 < 80; ++k4) {
                float4 wv = Wh4f[(size_t)k4 * G4n + c];
                float4 hv = h4[k4];
                ax += wv.x * hv.x; ay += wv.y * hv.y;
                az += wv.z * hv.z; aw += wv.w * hv.w;
            }
            gb[(size_t)((genN & 1) * Bn + b) * G4n + c] = ax + ay + az + aw;
        } else if (tid < 200) {
            const int lc = tid - 160;
            const int c = m * 40 + lc;
            float ax = 0.f, ay = 0.f, az = 0.f, aw = 0.f;
#pragma unroll 20
            for (int k4 = 0; k4 < 80; ++k4) {
                float4 wv = Wp4f[(size_t)k4 * Jn + c];
                float4 hv = h4[k4];
                ax += wv.x * hv.x; ay += wv.y * hv.y;
                az += wv.z * hv.z; aw += wv.w * hv.w;
            }
            float d = b_pred[c] + ax + ay + az + aw;
            dec_s[lc] = d;
            db[(size_t)((genN & 1) * Bn + b) * Jn + c] = d;
        }
        __syncthreads();   // dec_s ready
    }
    // ---- f slice: own 40 components ----
    if (tid < 40) {
        const int tc = tnew < (Tn - 1) ? tnew : (Tn - 1);
        f_s[tid] = fmaxf(xp[(size_t)(b * Tn + tc) * Jn + m * 40 + tid] + dec_s[tid], 0.0f);
    }
    __syncthreads();   // f_s ready
    // ---- partial logits over own k-slice, ALL 1025 columns ----
    {
        const float4* f4 = (const float4*)f_s;
        float4 fr[10];
#pragma unroll
        for (int j = 0; j < 10; ++j) fr[j] = f4[j];
        float* pw = pb + (size_t)((L & 1) * Bn + b) * 8 * 1028 + m * 1028;
        for (int c = tid; c < VP1; c += 320) {
            float ax = 0.f, ay = 0.f, az = 0.f, aw = 0.f;
#pragma unroll
            for (int j = 0; j < 10; ++j) {
                float4 wv = Wo4f[(size_t)(10 * m + j) * WO4S + c];
                float4 fv = fr[j];
                ax += wv.x * fv.x; ay += wv.y * fv.y;
                az += wv.z * fv.z; aw += wv.w * fv.w;
            }
            pw[c] = ax + ay + az + aw;
        }
    }
}

extern "C" void kernel_launch(void* const* d_in, const int* in_sizes, int n_in,
                              void* d_out, int out_size, void* d_ws, size_t ws_size,
                              hipStream_t stream) {
    (void)in_sizes; (void)n_in; (void)out_size; (void)ws_size;
    const float* x      = (const float*)d_in[0];
    const int*   outlen = (const int*)d_in[1];
    const float* W_enc  = (const float*)d_in[2];
    const float* b_enc  = (const float*)d_in[3];
    const float* Emb    = (const float*)d_in[4];
    const float* W_ih   = (const float*)d_in[5];
    const float* W_hh   = (const float*)d_in[6];
    const float* b_lstm = (const float*)d_in[7];
    const float* W_pred = (const float*)d_in[8];
    const float* b_pred = (const float*)d_in[9];
    const float* W_out  = (const float*)d_in[10];
    const float* b_out  = (const float*)d_in[11];

    float* ws  = (float*)d_ws;
    float* xp  = ws + OFF_XP;
    float* Gm  = ws + OFF_G;
    float* Wo4 = ws + OFF_WO4;
    float* Wh4 = ws + OFF_WH4;
    float* Wp4 = ws + OFF_WP4;
    float* cb  = ws + OFF_CB;
    float* db  = ws + OFF_DEC;
    float* gb  = ws + OFF_GB;
    float* pb  = ws + OFF_PB;
    int*   rec = (int*)(ws + OFF_REC);

    preamble<<<720, 256, 0, stream>>>(x, W_enc, b_enc, Emb, W_ih, b_lstm,
                                      W_hh, W_pred, W_out,
                                      xp, Gm, Wo4, Wh4, Wp4);

    for (int L = 0; L <= Sn; ++L)
        rnnt_step<<<256, 320, 0, stream>>>(xp, Gm, Wo4, Wh4, Wp4,
                                           b_out, b_lstm, b_pred, outlen,
                                           cb, db, gb, pb, rec,
                                           (float*)d_out, L);
}